// Round 5
// baseline (259.944 us; speedup 1.0000x reference)
//
#include <hip/hip_runtime.h>

#define NPTS    6144
#define DIM     32
#define NB      2
#define NCELL   1000          // 10x10x10, cell edge = 0.03 = radius
#define R2      0.0009f
#define LEAFBIT 8192
#define PPT     6             // points per thread in build phase (6144/1024)
#define NBCAP   128           // max neighbors kept per point (obs ~13)
#define CONS    256           // consumer blocks (48 rows each)
#define WPB     16            // waves per 1024-thread block
#define RPW     3             // rows per wave (16*3 = 48 rows/block)
#define MAGIC   0x7C3A91E5    // build-done flag value (!= any fill poison)

__device__ __forceinline__ int cellof(float x) {
    int c = (int)(x * (10.0f / 0.3f));
    return min(max(c, 0), 9);
}

// ---- ws layout (ints) ----
#define WS_LEAF   0      // [2] per-batch leaf counts
#define WS_FLAG   2      // [2] per-batch build-done flags (MAGIC when ready)
#define WS_CSTART 4      // [2*(NCELL+1)]
#define WS_SORTED 2008   // float4 [NB][NPTS], byte 8032 (16B aligned)

// Single launch. Blocks 0..NB-1: per-batch LDS histogram -> shfl scan ->
// cursor scatter into ws (the proven K1), then device-scope release of a
// MAGIC flag. Blocks NB..NB+CONS-1: pre-copy their non-leaf rows (overlaps
// the build; leaf[] is an input, not ws), spin on both flags, then run the
// proven refine body on their 48 rows. Ownership is by ORIGINAL index: every
// output row is written exactly once by exactly one wave -> no write races.
// Deadlock-safe: __launch_bounds__(1024,8) caps VGPR at 64 -> 2 blocks/CU
// -> capacity 512 >= 258, so all blocks are co-resident regardless of
// dispatch order; producers always make progress.
__global__ __launch_bounds__(1024, 8)
void fused(const float* __restrict__ points, const int* __restrict__ leaf,
           const float* __restrict__ emb,
           const float* __restrict__ W1, const float* __restrict__ b1,
           const float* __restrict__ W2, const float* __restrict__ b2,
           int* __restrict__ ws, float* __restrict__ out)
{
    __shared__ int s_hist[1024];
    __shared__ int s_cursor[1024];
    __shared__ int s_wsum[16];
    __shared__ int s_leaf;
    __shared__ __align__(16) float s_ei[WPB][DIM];
    __shared__ __align__(16) float s_mean[WPB][DIM];
    __shared__ float s_h[WPB][DIM];
    __shared__ int   s_nb[WPB][NBCAP];
    __shared__ int   s_sv[WPB][NBCAP];

    const int t = threadIdx.x;

    if (blockIdx.x < NB) {
        // ================= producer: build cell-sorted list in ws =========
        const int b = blockIdx.x;
        const int w = t >> 6, lane = t & 63;

        s_hist[t] = 0;
        if (t == 0) s_leaf = 0;

        float px[PPT], py[PPT], pz[PPT];
        int   pc[PPT], pw[PPT];

        __syncthreads();

        int lc = 0;
        #pragma unroll
        for (int r = 0; r < PPT; ++r) {
            const int i  = r * 1024 + t;
            const int gi = b * NPTS + i;
            px[r] = points[gi * 3 + 0];
            py[r] = points[gi * 3 + 1];
            pz[r] = points[gi * 3 + 2];
            const int lf = leaf[gi] > 0 ? 1 : 0;
            lc += lf;
            pc[r] = (cellof(pz[r]) * 10 + cellof(py[r])) * 10 + cellof(px[r]);
            pw[r] = i + (lf ? LEAFBIT : 0);
            atomicAdd(&s_hist[pc[r]], 1);
        }
        #pragma unroll
        for (int off = 32; off > 0; off >>= 1) lc += __shfl_down(lc, off);
        if (lane == 0) atomicAdd(&s_leaf, lc);
        __syncthreads();

        const int v = s_hist[t];
        int x = v;
        #pragma unroll
        for (int off = 1; off < 64; off <<= 1) {
            const int y = __shfl_up(x, off);
            if (lane >= off) x += y;
        }
        if (lane == 63) s_wsum[w] = x;
        __syncthreads();
        if (t < 16) {
            int wv = s_wsum[t];
            #pragma unroll
            for (int off = 1; off < 16; off <<= 1) {
                const int y = __shfl_up(wv, off);
                if (t >= off) wv += y;
            }
            s_wsum[t] = wv;
        }
        __syncthreads();
        const int incl = x + (w > 0 ? s_wsum[w - 1] : 0);
        s_cursor[t] = incl - v;

        if (t < NCELL) ws[WS_CSTART + b * (NCELL + 1) + t + 1] = incl;
        if (t == 0) {
            ws[WS_CSTART + b * (NCELL + 1)] = 0;
            ws[WS_LEAF + b] = s_leaf;
        }
        __syncthreads();

        float4* sorted = (float4*)(ws + WS_SORTED) + (size_t)b * NPTS;
        #pragma unroll
        for (int r = 0; r < PPT; ++r) {
            const int pos = atomicAdd(&s_cursor[pc[r]], 1);
            sorted[pos] = make_float4(px[r], py[r], pz[r], (float)pw[r]);
        }
        __syncthreads();
        if (t == 0) {
            __threadfence();                       // device-scope release
            __hip_atomic_store(&ws[WS_FLAG + b], MAGIC,
                               __ATOMIC_RELEASE, __HIP_MEMORY_SCOPE_AGENT);
        }
        return;
    }

    // ================= consumer: 48 owned rows =============================
    const int cblk  = blockIdx.x - NB;
    const int wid   = t >> 6;
    const int lane  = t & 63;
    const int gbase = cblk * (WPB * RPW) + wid * RPW;   // first owned row

    // ---- pre-spin: copy non-leaf rows (overlaps the build) ----
    {
        const int rr  = lane >> 3;          // 0..7; rows 0..2 valid
        const int sub = lane & 7;
        if (rr < RPW) {
            const int g = gbase + rr;
            if (leaf[g] <= 0) {             // non-leaf: final value is emb
                const float4* e4 = (const float4*)(emb + (size_t)g * DIM);
                float4*       o4 = (float4*)(out + (size_t)g * DIM);
                o4[sub] = e4[sub];
            }
        }
    }

    // ---- spin until both producers release ----
    if (t == 0) {
        while (__hip_atomic_load(&ws[WS_FLAG + 0], __ATOMIC_ACQUIRE,
                                 __HIP_MEMORY_SCOPE_AGENT) != MAGIC ||
               __hip_atomic_load(&ws[WS_FLAG + 1], __ATOMIC_ACQUIRE,
                                 __HIP_MEMORY_SCOPE_AGENT) != MAGIC)
            __builtin_amdgcn_s_sleep(2);
        __threadfence();
    }
    __syncthreads();

    const int dd   = lane & 31;
    const int half = lane >> 5;

    for (int rs = 0; rs < RPW; ++rs) {
        const int g  = gbase + rs;          // == b*NPTS + io
        if (leaf[g] <= 0) continue;         // copied pre-spin
        const int b  = (g >= NPTS) ? 1 : 0;
        const int io = g - b * NPTS;

        const float* embB = emb + (size_t)b * NPTS * DIM;
        float*       outR = out + (size_t)g * DIM;

        // ---- center embedding + norm via shfl tree ----
        float ev = 0.0f;
        if (lane < DIM) { ev = embB[(size_t)io * DIM + lane]; s_ei[wid][lane] = ev; }

        const bool ok = ws[WS_LEAF + b] >= 10;
        if (!ok) {                           // batch unchanged
            if (lane < DIM) outR[lane] = ev;
            continue;
        }

        float nsq = ev * ev;
        #pragma unroll
        for (int off = 16; off > 0; off >>= 1) nsq += __shfl_xor(nsq, off);
        const float ni2 = __shfl(nsq, 0);
        const float rni = 1.0f / fmaxf(sqrtf(ni2), 1e-8f);

        const float Px = points[g * 3 + 0];
        const float Py = points[g * 3 + 1];
        const float Pz = points[g * 3 + 2];
        const int cx = cellof(Px), cy = cellof(Py), cz = cellof(Pz);

        const int*    cst = ws + WS_CSTART + b * (NCELL + 1);
        const float4* srt = (const float4*)(ws + WS_SORTED) + (size_t)b * NPTS;

        int begv = 0, lenv = 0;
        if (lane < 9) {
            const int z = cz + lane / 3 - 1;
            const int y = cy + lane % 3 - 1;
            if ((unsigned)z <= 9u && (unsigned)y <= 9u) {
                const int rowb = (z * 10 + y) * 10;
                const int c0   = rowb + max(cx - 1, 0);
                const int c1   = rowb + min(cx + 1, 9);
                begv = cst[c0];
                lenv = cst[c1 + 1] - begv;
            }
        }
        const int rb0 = __shfl(begv, 0), rb1 = __shfl(begv, 1), rb2 = __shfl(begv, 2);
        const int rb3 = __shfl(begv, 3), rb4 = __shfl(begv, 4), rb5 = __shfl(begv, 5);
        const int rb6 = __shfl(begv, 6), rb7 = __shfl(begv, 7), rb8 = __shfl(begv, 8);
        const int ln0 = __shfl(lenv, 0), ln1 = __shfl(lenv, 1), ln2 = __shfl(lenv, 2);
        const int ln3 = __shfl(lenv, 3), ln4 = __shfl(lenv, 4), ln5 = __shfl(lenv, 5);
        const int ln6 = __shfl(lenv, 6), ln7 = __shfl(lenv, 7), ln8 = __shfl(lenv, 8);
        const int pf1 = ln0,       pf2 = pf1 + ln1, pf3 = pf2 + ln2;
        const int pf4 = pf3 + ln3, pf5 = pf4 + ln4, pf6 = pf5 + ln5;
        const int pf7 = pf6 + ln6, pf8 = pf7 + ln7, pf9 = pf8 + ln8;

        // ---- Phase A: scan candidates, compact nb hits into s_nb ----
        int nbcnt = 0;
        for (int base = 0; base < pf9; base += 64) {
            const int gg = base + lane;
            int j = 0;
            if (gg < pf9) j = rb8 + gg - pf8;
            if (gg < pf8) j = rb7 + gg - pf7;
            if (gg < pf7) j = rb6 + gg - pf6;
            if (gg < pf6) j = rb5 + gg - pf5;
            if (gg < pf5) j = rb4 + gg - pf4;
            if (gg < pf4) j = rb3 + gg - pf3;
            if (gg < pf3) j = rb2 + gg - pf2;
            if (gg < pf2) j = rb1 + gg - pf1;
            if (gg < pf1) j = rb0 + gg;
            const float4 Q  = srt[j];
            const float dx = Q.x - Px, dy = Q.y - Py, dz = Q.z - Pz;
            const float d2 = dx * dx + dy * dy + dz * dz;
            const int   jw = (int)Q.w;
            const bool  nb = (gg < pf9) && (d2 < R2) && ((jw & LEAFBIT) != 0);
            const unsigned long long m = __ballot(nb);
            if (nb) {
                const int pos = nbcnt + __popcll(m & ((1ull << lane) - 1ull));
                if (pos < NBCAP) s_nb[wid][pos] = jw & (LEAFBIT - 1);
            }
            nbcnt += __popcll(m);
        }
        const int cnt_nb = nbcnt;

        // ---- Phase B: cosine, 2 lanes per hit; survivors -> s_sv ----
        int csim = 0;
        const int nh = min(cnt_nb, NBCAP);
        for (int h0 = 0; h0 < nh; h0 += 32) {
            const int h = h0 + dd;
            float dot = 0.0f, nj2 = 0.0f;
            int   jo  = 0;
            if (h < nh) {
                jo = s_nb[wid][h];
                const float4* ej4 = (const float4*)(embB + (size_t)jo * DIM) + half * 4;
                #pragma unroll
                for (int k = 0; k < 4; ++k) {
                    const float4 vq = ej4[k];
                    const float4 a  = *(const float4*)&s_ei[wid][16 * half + 4 * k];
                    dot += a.x * vq.x + a.y * vq.y + a.z * vq.z + a.w * vq.w;
                    nj2 += vq.x * vq.x + vq.y * vq.y + vq.z * vq.z + vq.w * vq.w;
                }
            }
            dot += __shfl_xor(dot, 32);
            nj2 += __shfl_xor(nj2, 32);
            bool surv = false;
            if (h < nh && half == 0) {
                const float rnj = 1.0f / fmaxf(sqrtf(nj2), 1e-8f);
                surv = (dot * rni * rnj) > 0.7f;
            }
            const unsigned long long m = __ballot(surv);
            if (surv) {
                const int pos = csim + __popcll(m & ((1ull << lane) - 1ull));
                s_sv[wid][pos] = jo;
            }
            csim += __popcll(m);
        }

        if (!((cnt_nb > 1) && (csim > 0))) {     // wave-uniform: unchanged row
            if (lane < DIM) outR[lane] = ev;
            continue;
        }

        // ---- survivor mean: rows split across lane halves ----
        float msum = 0.0f;
        for (int vv = half; vv < csim; vv += 2)
            msum += embB[(size_t)s_sv[wid][vv] * DIM + dd];
        msum += __shfl_xor(msum, 32);
        if (half == 0) s_mean[wid][dd] = msum / (float)csim;

        // ---- MLP layer 1: k-range split across halves ----
        float a = (half == 0) ? b1[dd] : 0.0f;
        #pragma unroll
        for (int k = 0; k < 16; ++k) {
            const int kk = half * 16 + k;
            a = fmaf(s_ei[wid][kk], W1[kk * DIM + dd], a);
        }
        #pragma unroll
        for (int k = 0; k < 16; ++k) {
            const int kk = half * 16 + k;
            a = fmaf(s_mean[wid][kk], W1[(DIM + kk) * DIM + dd], a);
        }
        a += __shfl_xor(a, 32);
        if (half == 0) s_h[wid][dd] = fmaxf(a, 0.0f);

        // ---- MLP layer 2 ----
        float c = (half == 0) ? b2[dd] : 0.0f;
        #pragma unroll
        for (int k = 0; k < 16; ++k) {
            const int kk = half * 16 + k;
            c = fmaf(s_h[wid][kk], W2[kk * DIM + dd], c);
        }
        c += __shfl_xor(c, 32);
        if (half == 0)
            outR[dd] = c;
    }
}

extern "C" void kernel_launch(void* const* d_in, const int* in_sizes, int n_in,
                              void* d_out, int out_size, void* d_ws, size_t ws_size,
                              hipStream_t stream) {
    (void)in_sizes; (void)n_in; (void)out_size; (void)ws_size;
    const float* points = (const float*)d_in[0];
    const float* emb    = (const float*)d_in[1];
    const int*   leaf   = (const int*)d_in[2];
    const float* W1     = (const float*)d_in[3];
    const float* b1     = (const float*)d_in[4];
    const float* W2     = (const float*)d_in[5];
    const float* b2     = (const float*)d_in[6];
    float*       outp   = (float*)d_out;
    int*         ws     = (int*)d_ws;

    fused<<<NB + CONS, 1024, 0, stream>>>(points, leaf, emb,
                                          W1, b1, W2, b2, ws, outp);
}

// Round 6
// 226.883 us; speedup vs baseline: 1.1457x; 1.1457x over previous
//
#include <hip/hip_runtime.h>

#define NPTS    6144
#define DIM     32
#define NB      2
#define NCELL   1000          // 10x10x10, cell edge = 0.03 = radius
#define R2      0.0009f
#define LEAFBIT 8192
#define PPT     6             // points per thread in build phase (6144/1024)
#define NBCAP   128           // max neighbors kept per point (obs ~13)
#define CONS    254           // consumer blocks; NB+CONS = 256 = #CUs
#define WPB     16            // waves per 1024-thread block
#define NWAVES_C (CONS * WPB) // 4064 consumer waves
#define BASEROWS (NWAVES_C * 3)   // 12192; remaining 96 rows -> waves 0..95
#define GROWS   (NB * NPTS)   // 12288
#define MAGIC   0x7C3A91E5    // build-done flag (multi-byte, != any memset fill)

__device__ __forceinline__ int cellof(float x) {
    int c = (int)(x * (10.0f / 0.3f));
    return min(max(c, 0), 9);
}

// ---- ws layout (ints) ----
#define WS_LEAF   0      // [2] per-batch leaf counts
#define WS_FLAG   2      // [2] per-batch build-done flags (MAGIC when ready)
#define WS_CSTART 4      // [2*(NCELL+1)]
#define WS_SORTED 2008   // float4 [NB][NPTS], byte 8032 (16B aligned)

// Single launch, 256 blocks = 256 CUs (co-residency guaranteed at 1 block/CU:
// 31KB LDS, 64 VGPR -> no deadlock). Blocks 0..1: proven LDS-sort producer,
// device-scope MAGIC release. Blocks 2..255: pre-copy non-leaf rows
// (overlaps build), spin, then proven refine body. R5's failure was
// __launch_bounds__(1024,8) -> 32 VGPR -> 130MB scratch spill; bound removed.
__global__ __launch_bounds__(1024)
void fused(const float* __restrict__ points, const int* __restrict__ leaf,
           const float* __restrict__ emb,
           const float* __restrict__ W1, const float* __restrict__ b1,
           const float* __restrict__ W2, const float* __restrict__ b2,
           int* __restrict__ ws, float* __restrict__ out)
{
    __shared__ int s_hist[1024];
    __shared__ int s_cursor[1024];
    __shared__ int s_wsum[16];
    __shared__ int s_leaf;
    __shared__ __align__(16) float s_ei[WPB][DIM];
    __shared__ __align__(16) float s_mean[WPB][DIM];
    __shared__ float s_h[WPB][DIM];
    __shared__ int   s_nb[WPB][NBCAP];
    __shared__ int   s_sv[WPB][NBCAP];

    const int t = threadIdx.x;

    if (blockIdx.x < NB) {
        // ================= producer: build cell-sorted list in ws =========
        const int b = blockIdx.x;
        const int w = t >> 6, lane = t & 63;

        s_hist[t] = 0;
        if (t == 0) s_leaf = 0;

        float px[PPT], py[PPT], pz[PPT];
        int   pc[PPT], pw[PPT];

        __syncthreads();

        int lc = 0;
        #pragma unroll
        for (int r = 0; r < PPT; ++r) {
            const int i  = r * 1024 + t;
            const int gi = b * NPTS + i;
            px[r] = points[gi * 3 + 0];
            py[r] = points[gi * 3 + 1];
            pz[r] = points[gi * 3 + 2];
            const int lf = leaf[gi] > 0 ? 1 : 0;
            lc += lf;
            pc[r] = (cellof(pz[r]) * 10 + cellof(py[r])) * 10 + cellof(px[r]);
            pw[r] = i + (lf ? LEAFBIT : 0);
            atomicAdd(&s_hist[pc[r]], 1);
        }
        #pragma unroll
        for (int off = 32; off > 0; off >>= 1) lc += __shfl_down(lc, off);
        if (lane == 0) atomicAdd(&s_leaf, lc);
        __syncthreads();

        const int v = s_hist[t];
        int x = v;
        #pragma unroll
        for (int off = 1; off < 64; off <<= 1) {
            const int y = __shfl_up(x, off);
            if (lane >= off) x += y;
        }
        if (lane == 63) s_wsum[w] = x;
        __syncthreads();
        if (t < 16) {
            int wv = s_wsum[t];
            #pragma unroll
            for (int off = 1; off < 16; off <<= 1) {
                const int y = __shfl_up(wv, off);
                if (t >= off) wv += y;
            }
            s_wsum[t] = wv;
        }
        __syncthreads();
        const int incl = x + (w > 0 ? s_wsum[w - 1] : 0);
        s_cursor[t] = incl - v;

        if (t < NCELL) ws[WS_CSTART + b * (NCELL + 1) + t + 1] = incl;
        if (t == 0) {
            ws[WS_CSTART + b * (NCELL + 1)] = 0;
            ws[WS_LEAF + b] = s_leaf;
        }
        __syncthreads();

        float4* sorted = (float4*)(ws + WS_SORTED) + (size_t)b * NPTS;
        #pragma unroll
        for (int r = 0; r < PPT; ++r) {
            const int pos = atomicAdd(&s_cursor[pc[r]], 1);
            sorted[pos] = make_float4(px[r], py[r], pz[r], (float)pw[r]);
        }
        __syncthreads();
        if (t == 0) {
            __threadfence();                       // device-scope release
            __hip_atomic_store(&ws[WS_FLAG + b], MAGIC,
                               __ATOMIC_RELEASE, __HIP_MEMORY_SCOPE_AGENT);
        }
        return;
    }

    // ================= consumer: 3 (or 4) owned rows per wave ==============
    const int cblk = blockIdx.x - NB;
    const int wid  = t >> 6;
    const int lane = t & 63;
    const int wv   = cblk * WPB + wid;          // 0..4063
    const int nrows = (wv < GROWS - BASEROWS) ? 4 : 3;

    // owned row index for slot rs (rs in 0..3)
    #define OWNED(rs) ((rs) < 3 ? wv * 3 + (rs) : BASEROWS + wv)

    // ---- pre-spin: copy non-leaf rows (overlaps the build) ----
    {
        const int rr  = lane >> 3;              // 0..7; slots 0..nrows-1 valid
        const int sub = lane & 7;
        if (rr < nrows) {
            const int g = OWNED(rr);
            if (leaf[g] <= 0) {                 // non-leaf: final value is emb
                const float4* e4 = (const float4*)(emb + (size_t)g * DIM);
                float4*       o4 = (float4*)(out + (size_t)g * DIM);
                o4[sub] = e4[sub];
            }
        }
    }

    // ---- spin until both producers release ----
    if (t == 0) {
        while (__hip_atomic_load(&ws[WS_FLAG + 0], __ATOMIC_ACQUIRE,
                                 __HIP_MEMORY_SCOPE_AGENT) != MAGIC ||
               __hip_atomic_load(&ws[WS_FLAG + 1], __ATOMIC_ACQUIRE,
                                 __HIP_MEMORY_SCOPE_AGENT) != MAGIC)
            __builtin_amdgcn_s_sleep(2);
        __threadfence();
    }
    __syncthreads();

    const int dd   = lane & 31;
    const int half = lane >> 5;

    for (int rs = 0; rs < nrows; ++rs) {
        const int g  = OWNED(rs);               // == b*NPTS + io
        if (leaf[g] <= 0) continue;             // copied pre-spin
        const int b  = (g >= NPTS) ? 1 : 0;
        const int io = g - b * NPTS;

        const float* embB = emb + (size_t)b * NPTS * DIM;
        float*       outR = out + (size_t)g * DIM;

        // ---- center embedding + norm via shfl tree ----
        float ev = 0.0f;
        if (lane < DIM) { ev = embB[(size_t)io * DIM + lane]; s_ei[wid][lane] = ev; }

        if (ws[WS_LEAF + b] < 10) {             // batch unchanged
            if (lane < DIM) outR[lane] = ev;
            continue;
        }

        float nsq = ev * ev;
        #pragma unroll
        for (int off = 16; off > 0; off >>= 1) nsq += __shfl_xor(nsq, off);
        const float ni2 = __shfl(nsq, 0);
        const float rni = 1.0f / fmaxf(sqrtf(ni2), 1e-8f);

        const float Px = points[g * 3 + 0];
        const float Py = points[g * 3 + 1];
        const float Pz = points[g * 3 + 2];
        const int cx = cellof(Px), cy = cellof(Py), cz = cellof(Pz);

        const int*    cst = ws + WS_CSTART + b * (NCELL + 1);
        const float4* srt = (const float4*)(ws + WS_SORTED) + (size_t)b * NPTS;

        int begv = 0, lenv = 0;
        if (lane < 9) {
            const int z = cz + lane / 3 - 1;
            const int y = cy + lane % 3 - 1;
            if ((unsigned)z <= 9u && (unsigned)y <= 9u) {
                const int rowb = (z * 10 + y) * 10;
                const int c0   = rowb + max(cx - 1, 0);
                const int c1   = rowb + min(cx + 1, 9);
                begv = cst[c0];
                lenv = cst[c1 + 1] - begv;
            }
        }
        const int rb0 = __shfl(begv, 0), rb1 = __shfl(begv, 1), rb2 = __shfl(begv, 2);
        const int rb3 = __shfl(begv, 3), rb4 = __shfl(begv, 4), rb5 = __shfl(begv, 5);
        const int rb6 = __shfl(begv, 6), rb7 = __shfl(begv, 7), rb8 = __shfl(begv, 8);
        const int ln0 = __shfl(lenv, 0), ln1 = __shfl(lenv, 1), ln2 = __shfl(lenv, 2);
        const int ln3 = __shfl(lenv, 3), ln4 = __shfl(lenv, 4), ln5 = __shfl(lenv, 5);
        const int ln6 = __shfl(lenv, 6), ln7 = __shfl(lenv, 7), ln8 = __shfl(lenv, 8);
        const int pf1 = ln0,       pf2 = pf1 + ln1, pf3 = pf2 + ln2;
        const int pf4 = pf3 + ln3, pf5 = pf4 + ln4, pf6 = pf5 + ln5;
        const int pf7 = pf6 + ln6, pf8 = pf7 + ln7, pf9 = pf8 + ln8;

        // ---- Phase A: scan candidates, compact nb hits into s_nb ----
        int nbcnt = 0;
        for (int base = 0; base < pf9; base += 64) {
            const int gg = base + lane;
            int j = 0;
            if (gg < pf9) j = rb8 + gg - pf8;
            if (gg < pf8) j = rb7 + gg - pf7;
            if (gg < pf7) j = rb6 + gg - pf6;
            if (gg < pf6) j = rb5 + gg - pf5;
            if (gg < pf5) j = rb4 + gg - pf4;
            if (gg < pf4) j = rb3 + gg - pf3;
            if (gg < pf3) j = rb2 + gg - pf2;
            if (gg < pf2) j = rb1 + gg - pf1;
            if (gg < pf1) j = rb0 + gg;
            const float4 Q  = srt[j];
            const float dx = Q.x - Px, dy = Q.y - Py, dz = Q.z - Pz;
            const float d2 = dx * dx + dy * dy + dz * dz;
            const int   jw = (int)Q.w;
            const bool  nb = (gg < pf9) && (d2 < R2) && ((jw & LEAFBIT) != 0);
            const unsigned long long m = __ballot(nb);
            if (nb) {
                const int pos = nbcnt + __popcll(m & ((1ull << lane) - 1ull));
                if (pos < NBCAP) s_nb[wid][pos] = jw & (LEAFBIT - 1);
            }
            nbcnt += __popcll(m);
        }
        const int cnt_nb = nbcnt;

        // ---- Phase B: cosine, 2 lanes per hit; survivors -> s_sv ----
        int csim = 0;
        const int nh = min(cnt_nb, NBCAP);
        for (int h0 = 0; h0 < nh; h0 += 32) {
            const int h = h0 + dd;
            float dot = 0.0f, nj2 = 0.0f;
            int   jo  = 0;
            if (h < nh) {
                jo = s_nb[wid][h];
                const float4* ej4 = (const float4*)(embB + (size_t)jo * DIM) + half * 4;
                #pragma unroll
                for (int k = 0; k < 4; ++k) {
                    const float4 vq = ej4[k];
                    const float4 a  = *(const float4*)&s_ei[wid][16 * half + 4 * k];
                    dot += a.x * vq.x + a.y * vq.y + a.z * vq.z + a.w * vq.w;
                    nj2 += vq.x * vq.x + vq.y * vq.y + vq.z * vq.z + vq.w * vq.w;
                }
            }
            dot += __shfl_xor(dot, 32);
            nj2 += __shfl_xor(nj2, 32);
            bool surv = false;
            if (h < nh && half == 0) {
                const float rnj = 1.0f / fmaxf(sqrtf(nj2), 1e-8f);
                surv = (dot * rni * rnj) > 0.7f;
            }
            const unsigned long long m = __ballot(surv);
            if (surv) {
                const int pos = csim + __popcll(m & ((1ull << lane) - 1ull));
                s_sv[wid][pos] = jo;
            }
            csim += __popcll(m);
        }

        if (!((cnt_nb > 1) && (csim > 0))) {     // wave-uniform: unchanged row
            if (lane < DIM) outR[lane] = ev;
            continue;
        }

        // ---- survivor mean: rows split across lane halves ----
        float msum = 0.0f;
        for (int vv = half; vv < csim; vv += 2)
            msum += embB[(size_t)s_sv[wid][vv] * DIM + dd];
        msum += __shfl_xor(msum, 32);
        if (half == 0) s_mean[wid][dd] = msum / (float)csim;

        // ---- MLP layer 1: k-range split across halves ----
        float a = (half == 0) ? b1[dd] : 0.0f;
        #pragma unroll
        for (int k = 0; k < 16; ++k) {
            const int kk = half * 16 + k;
            a = fmaf(s_ei[wid][kk], W1[kk * DIM + dd], a);
        }
        #pragma unroll
        for (int k = 0; k < 16; ++k) {
            const int kk = half * 16 + k;
            a = fmaf(s_mean[wid][kk], W1[(DIM + kk) * DIM + dd], a);
        }
        a += __shfl_xor(a, 32);
        if (half == 0) s_h[wid][dd] = fmaxf(a, 0.0f);

        // ---- MLP layer 2 ----
        float c = (half == 0) ? b2[dd] : 0.0f;
        #pragma unroll
        for (int k = 0; k < 16; ++k) {
            const int kk = half * 16 + k;
            c = fmaf(s_h[wid][kk], W2[kk * DIM + dd], c);
        }
        c += __shfl_xor(c, 32);
        if (half == 0)
            outR[dd] = c;
    }
    #undef OWNED
}

extern "C" void kernel_launch(void* const* d_in, const int* in_sizes, int n_in,
                              void* d_out, int out_size, void* d_ws, size_t ws_size,
                              hipStream_t stream) {
    (void)in_sizes; (void)n_in; (void)out_size; (void)ws_size;
    const float* points = (const float*)d_in[0];
    const float* emb    = (const float*)d_in[1];
    const int*   leaf   = (const int*)d_in[2];
    const float* W1     = (const float*)d_in[3];
    const float* b1     = (const float*)d_in[4];
    const float* W2     = (const float*)d_in[5];
    const float* b2     = (const float*)d_in[6];
    float*       outp   = (float*)d_out;
    int*         ws     = (int*)d_ws;

    fused<<<NB + CONS, 1024, 0, stream>>>(points, leaf, emb,
                                          W1, b1, W2, b2, ws, outp);
}

// Round 7
// 87.748 us; speedup vs baseline: 2.9624x; 2.5856x over previous
//
#include <hip/hip_runtime.h>

#define NPTS    6144
#define DIM     32
#define NB      2
#define NCELL   1000          // 10x10x10, cell edge = 0.03 = radius
#define R2      0.0009f
#define NWAVES  4
#define BLOCK   (NWAVES * 64)
#define LEAFBIT 8192
#define PPT     6             // points per thread in build_cells (6144/1024)
#define NBCAP   128           // max neighbors kept per point (obs ~13)

__device__ __forceinline__ int cellof(float x) {
    int c = (int)(x * (10.0f / 0.3f));
    return min(max(c, 0), 9);
}

// ---- ws layout (ints) ----
#define WS_LEAF   0
#define WS_CSTART 4
#define WS_SORTED 2008   // float4 [NB][NPTS], byte 8032 (16B aligned)

// Session verdict (R0-R6): this two-launch structure is the optimum.
// Single-launch variants all lost: per-block LDS rebuild thrashes L2
// (R3: 61MB fetch, 135us), producer-consumer flag handoff invalidates
// caches across XCDs (R6: 41MB fetch, 8% HBM, 227us), min-waves bounds
// spill (R5: 130MB scratch writes, 260us). Micro-opts inside refine were
// neutral-to-negative (R1 +0.8us, R4 +5.7us). Measured floor: ~86us, of
// which ~70us is harness-side (40us 256MB ws-poison fill at 80% HBM peak
// + memsets + 2 launch gaps); both kernels combined are under ~15us.

// K1: one block per batch. LDS histogram -> shfl scan -> LDS-cursor scatter.
__global__ __launch_bounds__(1024)
void build_cells(const float* __restrict__ points, const int* __restrict__ leaf,
                 int* __restrict__ ws)
{
    __shared__ int s_hist[1024];
    __shared__ int s_cursor[1024];
    __shared__ int s_wsum[16];
    __shared__ int s_leaf;

    const int t = threadIdx.x;
    const int b = blockIdx.x;
    const int w = t >> 6, lane = t & 63;

    s_hist[t] = 0;
    if (t == 0) s_leaf = 0;

    float px[PPT], py[PPT], pz[PPT];
    int   pc[PPT], pw[PPT];

    __syncthreads();

    int lc = 0;
    #pragma unroll
    for (int r = 0; r < PPT; ++r) {
        const int i  = r * 1024 + t;
        const int gi = b * NPTS + i;
        px[r] = points[gi * 3 + 0];
        py[r] = points[gi * 3 + 1];
        pz[r] = points[gi * 3 + 2];
        const int lf = leaf[gi] > 0 ? 1 : 0;
        lc += lf;
        pc[r] = (cellof(pz[r]) * 10 + cellof(py[r])) * 10 + cellof(px[r]);
        pw[r] = i + (lf ? LEAFBIT : 0);
        atomicAdd(&s_hist[pc[r]], 1);
    }
    #pragma unroll
    for (int off = 32; off > 0; off >>= 1) lc += __shfl_down(lc, off);
    if (lane == 0) atomicAdd(&s_leaf, lc);
    __syncthreads();

    const int v = s_hist[t];
    int x = v;
    #pragma unroll
    for (int off = 1; off < 64; off <<= 1) {
        const int y = __shfl_up(x, off);
        if (lane >= off) x += y;
    }
    if (lane == 63) s_wsum[w] = x;
    __syncthreads();
    if (t < 16) {
        int wv = s_wsum[t];
        #pragma unroll
        for (int off = 1; off < 16; off <<= 1) {
            const int y = __shfl_up(wv, off);
            if (t >= off) wv += y;
        }
        s_wsum[t] = wv;
    }
    __syncthreads();
    const int incl = x + (w > 0 ? s_wsum[w - 1] : 0);
    s_cursor[t] = incl - v;

    if (t < NCELL) ws[WS_CSTART + b * (NCELL + 1) + t + 1] = incl;
    if (t == 0) {
        ws[WS_CSTART + b * (NCELL + 1)] = 0;
        ws[WS_LEAF + b] = s_leaf;
    }
    __syncthreads();

    float4* sorted = (float4*)(ws + WS_SORTED) + (size_t)b * NPTS;
    #pragma unroll
    for (int r = 0; r < PPT; ++r) {
        const int pos = atomicAdd(&s_cursor[pc[r]], 1);
        sorted[pos] = make_float4(px[r], py[r], pz[r], (float)pw[r]);
    }
}

// K2: wave per point. Non-leaf (or invalid-batch) waves exit immediately with
// a float4 copy — cond can only hold for leaf points, so ~50% of waves skip
// the scan entirely. Leaf waves: concatenated 9-run scan -> compact hits ->
// lane-per-hit cosine -> atomic-free survivor mean -> MLP (direct L2 weight
// reads; no barriers anywhere in this kernel).
__global__ __launch_bounds__(BLOCK)
void refine(const float* __restrict__ emb,
            const float* __restrict__ W1, const float* __restrict__ b1,
            const float* __restrict__ W2, const float* __restrict__ b2,
            const int* __restrict__ ws, float* __restrict__ out)
{
    __shared__ __align__(16) float s_ei[NWAVES][DIM];
    __shared__ float s_mean[NWAVES][DIM];
    __shared__ float s_h[NWAVES][DIM];
    __shared__ int   s_nb[NWAVES][NBCAP];
    __shared__ int   s_sv[NWAVES][NBCAP];

    const int tid  = threadIdx.x;
    const int wid  = tid >> 6;
    const int lane = tid & 63;
    const int s    = blockIdx.x * NWAVES + wid;
    const int b    = s / NPTS;
    const int slot = s - b * NPTS;

    const float4* srt  = (const float4*)(ws + WS_SORTED) + (size_t)b * NPTS;
    const int*    cst  = ws + WS_CSTART + b * (NCELL + 1);
    const float*  embB = emb + (size_t)b * NPTS * DIM;

    const float4 P  = srt[slot];
    const int    iw = (int)P.w;
    const int    io = iw & (LEAFBIT - 1);
    const bool   li = (iw & LEAFBIT) != 0;
    const bool   ok = ws[WS_LEAF + b] >= 10;

    const float4* e4   = (const float4*)(embB + (size_t)io * DIM);
    float4*       out4 = (float4*)(out + ((size_t)b * NPTS + io) * DIM);

    // ---- early exit: cond requires ok && li; everything else is a copy ----
    if (!(ok && li)) {                   // wave-uniform
        if (lane < DIM / 4) out4[lane] = e4[lane];
        return;
    }

    if (lane < DIM) s_ei[wid][lane] = ((const float*)e4)[lane];

    float ni2 = 0.0f;
    #pragma unroll
    for (int d = 0; d < DIM; ++d) { const float v = s_ei[wid][d]; ni2 += v * v; }
    const float rni = 1.0f / fmaxf(sqrtf(ni2), 1e-8f);

    const int cx = cellof(P.x), cy = cellof(P.y), cz = cellof(P.z);

    int begv = 0, lenv = 0;
    if (lane < 9) {
        const int z = cz + lane / 3 - 1;
        const int y = cy + lane % 3 - 1;
        if ((unsigned)z <= 9u && (unsigned)y <= 9u) {
            const int rowb = (z * 10 + y) * 10;
            const int c0   = rowb + max(cx - 1, 0);
            const int c1   = rowb + min(cx + 1, 9);
            begv = cst[c0];
            lenv = cst[c1 + 1] - begv;
        }
    }
    const int rb0 = __shfl(begv, 0), rb1 = __shfl(begv, 1), rb2 = __shfl(begv, 2);
    const int rb3 = __shfl(begv, 3), rb4 = __shfl(begv, 4), rb5 = __shfl(begv, 5);
    const int rb6 = __shfl(begv, 6), rb7 = __shfl(begv, 7), rb8 = __shfl(begv, 8);
    const int ln0 = __shfl(lenv, 0), ln1 = __shfl(lenv, 1), ln2 = __shfl(lenv, 2);
    const int ln3 = __shfl(lenv, 3), ln4 = __shfl(lenv, 4), ln5 = __shfl(lenv, 5);
    const int ln6 = __shfl(lenv, 6), ln7 = __shfl(lenv, 7), ln8 = __shfl(lenv, 8);
    const int pf1 = ln0,       pf2 = pf1 + ln1, pf3 = pf2 + ln2;
    const int pf4 = pf3 + ln3, pf5 = pf4 + ln4, pf6 = pf5 + ln5;
    const int pf7 = pf6 + ln6, pf8 = pf7 + ln7, pf9 = pf8 + ln8;

    // ---- Phase A: scan candidates, compact nb hits into s_nb ----
    int nbcnt = 0;
    for (int base = 0; base < pf9; base += 64) {
        const int g = base + lane;
        int j = 0;
        if (g < pf9) j = rb8 + g - pf8;
        if (g < pf8) j = rb7 + g - pf7;
        if (g < pf7) j = rb6 + g - pf6;
        if (g < pf6) j = rb5 + g - pf5;
        if (g < pf5) j = rb4 + g - pf4;
        if (g < pf4) j = rb3 + g - pf3;
        if (g < pf3) j = rb2 + g - pf2;
        if (g < pf2) j = rb1 + g - pf1;
        if (g < pf1) j = rb0 + g;
        const float4 Q  = srt[j];
        const float dx = Q.x - P.x, dy = Q.y - P.y, dz = Q.z - P.z;
        const float d2 = dx * dx + dy * dy + dz * dz;
        const int   jw = (int)Q.w;
        const bool  nb = (g < pf9) && (d2 < R2) && ((jw & LEAFBIT) != 0);
        const unsigned long long m = __ballot(nb);
        if (nb) {
            const int pos = nbcnt + __popcll(m & ((1ull << lane) - 1ull));
            if (pos < NBCAP) s_nb[wid][pos] = jw & (LEAFBIT - 1);
        }
        nbcnt += __popcll(m);
    }
    const int cnt_nb = nbcnt;

    // ---- Phase B: cosine per hit; survivors -> s_sv via ballot prefix ----
    int csim = 0;
    const int nh = min(cnt_nb, NBCAP);
    for (int h0 = 0; h0 < nh; h0 += 64) {
        const int h = h0 + lane;
        bool surv = false;
        int  jo   = 0;
        if (h < nh) {
            jo = s_nb[wid][h];
            const float4* ej4 = (const float4*)(embB + (size_t)jo * DIM);
            float dot = 0.0f, nj2 = 0.0f;
            #pragma unroll
            for (int k = 0; k < DIM / 4; ++k) {
                const float4 v = ej4[k];
                const float4 a = *(const float4*)&s_ei[wid][4 * k];
                dot += a.x * v.x + a.y * v.y + a.z * v.z + a.w * v.w;
                nj2 += v.x * v.x + v.y * v.y + v.z * v.z + v.w * v.w;
            }
            const float rnj = 1.0f / fmaxf(sqrtf(nj2), 1e-8f);
            surv = (dot * rni * rnj) > 0.7f;
        }
        const unsigned long long m = __ballot(surv);
        if (surv) {
            const int pos = csim + __popcll(m & ((1ull << lane) - 1ull));
            s_sv[wid][pos] = jo;
        }
        csim += __popcll(m);
    }

    const bool cond = (cnt_nb > 1) && (csim > 0);   // wave-uniform (ok&&li held)

    if (lane < DIM) {
        if (!cond) {
            out[((size_t)b * NPTS + io) * DIM + lane] = s_ei[wid][lane];
        } else {
            // atomic-free survivor mean (coalesced per-survivor rows)
            float msum = 0.0f;
            for (int v = 0; v < csim; ++v)
                msum += embB[(size_t)s_sv[wid][v] * DIM + lane];
            s_mean[wid][lane] = msum / (float)csim;

            float a0 = b1[lane], a1 = 0.0f;
            #pragma unroll
            for (int k = 0; k < DIM; k += 2) {
                a0 = fmaf(s_ei[wid][k],     W1[k * DIM + lane],       a0);
                a1 = fmaf(s_ei[wid][k + 1], W1[(k + 1) * DIM + lane], a1);
            }
            #pragma unroll
            for (int k = 0; k < DIM; k += 2) {
                a0 = fmaf(s_mean[wid][k],     W1[(DIM + k) * DIM + lane],     a0);
                a1 = fmaf(s_mean[wid][k + 1], W1[(DIM + k + 1) * DIM + lane], a1);
            }
            s_h[wid][lane] = fmaxf(a0 + a1, 0.0f);
            float c0 = b2[lane], c1 = 0.0f;
            #pragma unroll
            for (int k = 0; k < DIM; k += 2) {
                c0 = fmaf(s_h[wid][k],     W2[k * DIM + lane],       c0);
                c1 = fmaf(s_h[wid][k + 1], W2[(k + 1) * DIM + lane], c1);
            }
            out[((size_t)b * NPTS + io) * DIM + lane] = c0 + c1;
        }
    }
}

extern "C" void kernel_launch(void* const* d_in, const int* in_sizes, int n_in,
                              void* d_out, int out_size, void* d_ws, size_t ws_size,
                              hipStream_t stream) {
    const float* points = (const float*)d_in[0];
    const float* emb    = (const float*)d_in[1];
    const int*   leaf   = (const int*)d_in[2];
    const float* W1     = (const float*)d_in[3];
    const float* b1     = (const float*)d_in[4];
    const float* W2     = (const float*)d_in[5];
    const float* b2     = (const float*)d_in[6];
    float*       outp   = (float*)d_out;
    int*         ws     = (int*)d_ws;

    build_cells<<<NB, 1024, 0, stream>>>(points, leaf, ws);

    const int grid = (NB * NPTS) / NWAVES;                       // 3072
    refine<<<grid, BLOCK, 0, stream>>>(emb, W1, b1, W2, b2, ws, outp);
}